// Round 4
// baseline (14234.042 us; speedup 1.0000x reference)
//
#include <hip/hip_runtime.h>

#define NN 50000
#define EE 800000
#define DIN 128
#define DH 64
#define CC 4
#define LL 3

typedef float f32x16 __attribute__((ext_vector_type(16)));

__device__ __forceinline__ float sigmoidf_(float x) {
    return __builtin_amdgcn_rcpf(1.0f + __expf(-x));
}

// ---- register-resident 16-wide helpers (all vector indices are literals) ----
#define LOAD16(V, P) { const float4* _p4 = (const float4*)(P); \
    float4 _a=_p4[0], _b=_p4[1], _c=_p4[2], _d=_p4[3]; \
    V[0]=_a.x; V[1]=_a.y; V[2]=_a.z; V[3]=_a.w; \
    V[4]=_b.x; V[5]=_b.y; V[6]=_b.z; V[7]=_b.w; \
    V[8]=_c.x; V[9]=_c.y; V[10]=_c.z; V[11]=_c.w; \
    V[12]=_d.x; V[13]=_d.y; V[14]=_d.z; V[15]=_d.w; }

#define FMA16V(V, P, xv) { const float4* _w4 = (const float4*)(P); \
    float4 _w0=_w4[0], _w1=_w4[1], _w2=_w4[2], _w3=_w4[3]; \
    V[0]+=(xv)*_w0.x; V[1]+=(xv)*_w0.y; V[2]+=(xv)*_w0.z; V[3]+=(xv)*_w0.w; \
    V[4]+=(xv)*_w1.x; V[5]+=(xv)*_w1.y; V[6]+=(xv)*_w1.z; V[7]+=(xv)*_w1.w; \
    V[8]+=(xv)*_w2.x; V[9]+=(xv)*_w2.y; V[10]+=(xv)*_w2.z; V[11]+=(xv)*_w2.w; \
    V[12]+=(xv)*_w3.x; V[13]+=(xv)*_w3.y; V[14]+=(xv)*_w3.z; V[15]+=(xv)*_w3.w; }

#define FMA64V(V0,V1,V2,V3, ROWP, xv) { const float* _rp = (ROWP); const float _x = (xv); \
    FMA16V(V0, _rp+0, _x) FMA16V(V1, _rp+16, _x) FMA16V(V2, _rp+32, _x) FMA16V(V3, _rp+48, _x) }

#define SILU16(V) { \
    V[0]*=sigmoidf_(V[0]);  V[1]*=sigmoidf_(V[1]);  V[2]*=sigmoidf_(V[2]);  V[3]*=sigmoidf_(V[3]); \
    V[4]*=sigmoidf_(V[4]);  V[5]*=sigmoidf_(V[5]);  V[6]*=sigmoidf_(V[6]);  V[7]*=sigmoidf_(V[7]); \
    V[8]*=sigmoidf_(V[8]);  V[9]*=sigmoidf_(V[9]);  V[10]*=sigmoidf_(V[10]); V[11]*=sigmoidf_(V[11]); \
    V[12]*=sigmoidf_(V[12]); V[13]*=sigmoidf_(V[13]); V[14]*=sigmoidf_(V[14]); V[15]*=sigmoidf_(V[15]); }

#define MUL16(V, s) { \
    V[0]*=(s); V[1]*=(s); V[2]*=(s); V[3]*=(s); V[4]*=(s); V[5]*=(s); V[6]*=(s); V[7]*=(s); \
    V[8]*=(s); V[9]*=(s); V[10]*=(s); V[11]*=(s); V[12]*=(s); V[13]*=(s); V[14]*=(s); V[15]*=(s); }

#define DOT16(acc, V, P) { const float4* _g4 = (const float4*)(P); \
    float4 _g0=_g4[0], _g1=_g4[1], _g2=_g4[2], _g3=_g4[3]; \
    acc += V[0]*_g0.x + V[1]*_g0.y + V[2]*_g0.z + V[3]*_g0.w \
         + V[4]*_g1.x + V[5]*_g1.y + V[6]*_g1.z + V[7]*_g1.w \
         + V[8]*_g2.x + V[9]*_g2.y + V[10]*_g2.z + V[11]*_g2.w \
         + V[12]*_g3.x + V[13]*_g3.y + V[14]*_g3.z + V[15]*_g3.w; }

#define ATOM16(P, V) { \
    atomicAdd((P)+0,  V[0]);  atomicAdd((P)+1,  V[1]);  atomicAdd((P)+2,  V[2]);  atomicAdd((P)+3,  V[3]); \
    atomicAdd((P)+4,  V[4]);  atomicAdd((P)+5,  V[5]);  atomicAdd((P)+6,  V[6]);  atomicAdd((P)+7,  V[7]); \
    atomicAdd((P)+8,  V[8]);  atomicAdd((P)+9,  V[9]);  atomicAdd((P)+10, V[10]); atomicAdd((P)+11, V[11]); \
    atomicAdd((P)+12, V[12]); atomicAdd((P)+13, V[13]); atomicAdd((P)+14, V[14]); atomicAdd((P)+15, V[15]); }

#define GSTEP(D0,D1,D2,D3, W, kk, xv) FMA64V(D0,D1,D2,D3, (W)+(size_t)(kk)*DH, xv)
#define GEMM16(D0,D1,D2,D3, S, W, ko) \
    GSTEP(D0,D1,D2,D3, W, (ko)+0,  S[0])  GSTEP(D0,D1,D2,D3, W, (ko)+1,  S[1])  \
    GSTEP(D0,D1,D2,D3, W, (ko)+2,  S[2])  GSTEP(D0,D1,D2,D3, W, (ko)+3,  S[3])  \
    GSTEP(D0,D1,D2,D3, W, (ko)+4,  S[4])  GSTEP(D0,D1,D2,D3, W, (ko)+5,  S[5])  \
    GSTEP(D0,D1,D2,D3, W, (ko)+6,  S[6])  GSTEP(D0,D1,D2,D3, W, (ko)+7,  S[7])  \
    GSTEP(D0,D1,D2,D3, W, (ko)+8,  S[8])  GSTEP(D0,D1,D2,D3, W, (ko)+9,  S[9])  \
    GSTEP(D0,D1,D2,D3, W, (ko)+10, S[10]) GSTEP(D0,D1,D2,D3, W, (ko)+11, S[11]) \
    GSTEP(D0,D1,D2,D3, W, (ko)+12, S[12]) GSTEP(D0,D1,D2,D3, W, (ko)+13, S[13]) \
    GSTEP(D0,D1,D2,D3, W, (ko)+14, S[14]) GSTEP(D0,D1,D2,D3, W, (ko)+15, S[15])

// ---- segmented wave reduction (dst-sorted edges; reduce run -> head lane) ----
#define SEG16(V, S, okf) { \
    float _r0=__shfl_down(V[0],S),  _r1=__shfl_down(V[1],S),  _r2=__shfl_down(V[2],S),  _r3=__shfl_down(V[3],S), \
          _r4=__shfl_down(V[4],S),  _r5=__shfl_down(V[5],S),  _r6=__shfl_down(V[6],S),  _r7=__shfl_down(V[7],S), \
          _r8=__shfl_down(V[8],S),  _r9=__shfl_down(V[9],S),  _r10=__shfl_down(V[10],S), _r11=__shfl_down(V[11],S), \
          _r12=__shfl_down(V[12],S), _r13=__shfl_down(V[13],S), _r14=__shfl_down(V[14],S), _r15=__shfl_down(V[15],S); \
    V[0]=fmaf(okf,_r0,V[0]);   V[1]=fmaf(okf,_r1,V[1]);   V[2]=fmaf(okf,_r2,V[2]);   V[3]=fmaf(okf,_r3,V[3]); \
    V[4]=fmaf(okf,_r4,V[4]);   V[5]=fmaf(okf,_r5,V[5]);   V[6]=fmaf(okf,_r6,V[6]);   V[7]=fmaf(okf,_r7,V[7]); \
    V[8]=fmaf(okf,_r8,V[8]);   V[9]=fmaf(okf,_r9,V[9]);   V[10]=fmaf(okf,_r10,V[10]); V[11]=fmaf(okf,_r11,V[11]); \
    V[12]=fmaf(okf,_r12,V[12]); V[13]=fmaf(okf,_r13,V[13]); V[14]=fmaf(okf,_r14,V[14]); V[15]=fmaf(okf,_r15,V[15]); }

#define SEGSTEP(S) { \
    int _tn = __shfl_down(tkey, S); \
    float _ok = ((lane + S < 64) && (_tn == tkey)) ? 1.0f : 0.0f; \
    SEG16(B0v, S, _ok) SEG16(B1v, S, _ok) SEG16(B2v, S, _ok) SEG16(B3v, S, _ok) \
    { float _a=__shfl_down(tx,S), _b=__shfl_down(ty,S), _c=__shfl_down(tz,S); \
      tx=fmaf(_ok,_a,tx); ty=fmaf(_ok,_b,ty); tz=fmaf(_ok,_c,tz); } }

// ---------------- degree count (once per launch) ----------------
__global__ void cnt_kernel(const int* __restrict__ dst, int* __restrict__ cnt, int E) {
    int e = blockIdx.x * 256 + threadIdx.x;
    if (e < E) atomicAdd(&cnt[dst[e]], 1);
}

// ---------------- 3-step exclusive scan of cnt -> offs ----------------
__global__ __launch_bounds__(256) void scan1(const int* __restrict__ cnt, int* __restrict__ offs,
                                             int* __restrict__ bsum, int N) {
    __shared__ int sh[256];
    int i = blockIdx.x * 256 + threadIdx.x;
    int v = (i < N) ? cnt[i] : 0;
    sh[threadIdx.x] = v; __syncthreads();
    for (int s = 1; s < 256; s <<= 1) {
        int a = (threadIdx.x >= s) ? sh[threadIdx.x - s] : 0;
        __syncthreads(); sh[threadIdx.x] += a; __syncthreads();
    }
    int incl = sh[threadIdx.x];
    if (i < N) offs[i] = incl - v;
    if (threadIdx.x == 255) bsum[blockIdx.x] = incl;
}
__global__ __launch_bounds__(256) void scan2(int* __restrict__ bsum, int nb) {
    __shared__ int sh[256];
    int v = (threadIdx.x < nb) ? bsum[threadIdx.x] : 0;
    sh[threadIdx.x] = v; __syncthreads();
    for (int s = 1; s < 256; s <<= 1) {
        int a = (threadIdx.x >= s) ? sh[threadIdx.x - s] : 0;
        __syncthreads(); sh[threadIdx.x] += a; __syncthreads();
    }
    if (threadIdx.x < nb) bsum[threadIdx.x] = sh[threadIdx.x] - v;
}
__global__ void scan3(int* __restrict__ offs, const int* __restrict__ bsum, int N) {
    int i = blockIdx.x * 256 + threadIdx.x;
    if (i < N) offs[i] += bsum[blockIdx.x];
}

// ---------------- counting-sort edges by dst ----------------
__global__ void order_kernel(const int* __restrict__ src, const int* __restrict__ dst,
                             const int* __restrict__ offs, int* __restrict__ fill,
                             int* __restrict__ ssrc, int* __restrict__ sdst, int E) {
    int e = blockIdx.x * 256 + threadIdx.x;
    if (e < E) {
        int d = dst[e];
        int slot = offs[d] + atomicAdd(&fill[d], 1);
        ssrc[slot] = src[e];
        sdst[slot] = d;
    }
}

// ---------------- mix_in ----------------
__global__ __launch_bounds__(256) void mix_in_kernel(
        const float* __restrict__ x, const float* __restrict__ W,
        float* __restrict__ h, int N) {
    __shared__ float xs[8][DIN];
    const int i0 = blockIdx.x * 8;
    const int tid = threadIdx.x;
    for (int t = tid; t < 8 * DIN; t += 256) {
        int j = t / DIN, k = t % DIN;
        int i = i0 + j;
        xs[j][k] = (i < N) ? x[(size_t)i * DIN + k] : 0.f;
    }
    __syncthreads();
    float acc[8] = {0.f, 0.f, 0.f, 0.f, 0.f, 0.f, 0.f, 0.f};
    for (int k = 0; k < DIN; ++k) {
        float w = W[k * (CC * DH) + tid];
        #pragma unroll
        for (int j = 0; j < 8; ++j) acc[j] += xs[j][k] * w;
    }
    const int c = tid >> 6, d = tid & 63;
    #pragma unroll
    for (int j = 0; j < 8; ++j) {
        int i = i0 + j;
        if (i < N) h[((size_t)c * N + i) * DH + d] = acc[j];
    }
}

// ---------------- edge kernel: LDS-staged weights, dst-sorted, segmented reduce ----------------
__global__ __launch_bounds__(512, 4) void edge_kernel(
    const float* __restrict__ h, const float* __restrict__ pos,
    const int* __restrict__ ssrc, const int* __restrict__ sdst,
    const float* __restrict__ ew1, const float* __restrict__ eb1,
    const float* __restrict__ ew2, const float* __restrict__ eb2,
    const float* __restrict__ gw,  const float* __restrict__ gb,
    const float* __restrict__ pw1, const float* __restrict__ pb1,
    const float* __restrict__ pw2,
    float* __restrict__ agg, float* __restrict__ pos_acc,
    int E, int N)
{
    __shared__ float sW1[(2 * DH + 1) * DH];   // 8256 floats
    __shared__ float sW2[DH * DH];             // 4096
    __shared__ float sPW1[DH * DH];            // 4096
    __shared__ float sB1[DH], sB2[DH], sPB1[DH], sGW[DH], sPW2[DH];

    const int c = blockIdx.y;
    const int tid = threadIdx.x;

    // ---- stage weights to LDS (coalesced float4 copies) ----
    {
        const float4* g1 = (const float4*)(ew1 + (size_t)c * (2 * DH + 1) * DH);
        float4* l1 = (float4*)sW1;
        #pragma unroll
        for (int i = 0; i < 5; ++i) { int idx = tid + i * 512; if (idx < 2064) l1[idx] = g1[idx]; }
        const float4* g2 = (const float4*)(ew2 + (size_t)c * DH * DH);
        float4* l2 = (float4*)sW2;
        l2[tid] = g2[tid];
        l2[tid + 512] = g2[tid + 512];
        const float4* g3 = (const float4*)(pw1 + (size_t)c * DH * DH);
        float4* l3 = (float4*)sPW1;
        l3[tid] = g3[tid];
        l3[tid + 512] = g3[tid + 512];
        if (tid < DH) {
            sB1[tid]  = eb1[(size_t)c * DH + tid];
            sB2[tid]  = eb2[(size_t)c * DH + tid];
            sPB1[tid] = pb1[(size_t)c * DH + tid];
            sGW[tid]  = gw[(size_t)c * DH + tid];
            sPW2[tid] = pw2[(size_t)c * DH + tid];
        }
    }
    __syncthreads();

    const int e = blockIdx.x * 512 + tid;
    const int lane = tid & 63;
    int s, t, tkey;
    if (e < E) { s = ssrc[e]; t = sdst[e]; tkey = t; }
    else       { s = 0;       t = 0;       tkey = -1; }

    const float rx = pos[s * 3 + 0] - pos[t * 3 + 0];
    const float ry = pos[s * 3 + 1] - pos[t * 3 + 1];
    const float rz = pos[s * 3 + 2] - pos[t * 3 + 2];
    const float d2 = rx * rx + ry * ry + rz * rz;

    const float GB = gb[c];
    const float4* hs4 = (const float4*)(h + ((size_t)c * N + s) * DH);
    const float4* hd4 = (const float4*)(h + ((size_t)c * N + t) * DH);

    // ---- m1 = silu([h_s, h_d, d2] @ W1 + B1) ----
    f32x16 A0, A1, A2, A3;
    LOAD16(A0, sB1 + 0) LOAD16(A1, sB1 + 16) LOAD16(A2, sB1 + 32) LOAD16(A3, sB1 + 48)
    #pragma unroll 2
    for (int k4 = 0; k4 < 16; ++k4) {
        const float4 xa = hs4[k4];
        FMA64V(A0,A1,A2,A3, sW1 + (size_t)(k4*4+0)*DH, xa.x)
        FMA64V(A0,A1,A2,A3, sW1 + (size_t)(k4*4+1)*DH, xa.y)
        FMA64V(A0,A1,A2,A3, sW1 + (size_t)(k4*4+2)*DH, xa.z)
        FMA64V(A0,A1,A2,A3, sW1 + (size_t)(k4*4+3)*DH, xa.w)
    }
    #pragma unroll 2
    for (int k4 = 0; k4 < 16; ++k4) {
        const float4 xa = hd4[k4];
        FMA64V(A0,A1,A2,A3, sW1 + (size_t)(DH + k4*4+0)*DH, xa.x)
        FMA64V(A0,A1,A2,A3, sW1 + (size_t)(DH + k4*4+1)*DH, xa.y)
        FMA64V(A0,A1,A2,A3, sW1 + (size_t)(DH + k4*4+2)*DH, xa.z)
        FMA64V(A0,A1,A2,A3, sW1 + (size_t)(DH + k4*4+3)*DH, xa.w)
    }
    FMA64V(A0,A1,A2,A3, sW1 + (size_t)(2*DH)*DH, d2)
    SILU16(A0) SILU16(A1) SILU16(A2) SILU16(A3)

    // ---- m2 = silu(m1 @ W2 + B2) ----
    f32x16 B0v, B1v, B2v, B3v;
    LOAD16(B0v, sB2 + 0) LOAD16(B1v, sB2 + 16) LOAD16(B2v, sB2 + 32) LOAD16(B3v, sB2 + 48)
    GEMM16(B0v,B1v,B2v,B3v, A0, sW2, 0)
    GEMM16(B0v,B1v,B2v,B3v, A1, sW2, 16)
    GEMM16(B0v,B1v,B2v,B3v, A2, sW2, 32)
    GEMM16(B0v,B1v,B2v,B3v, A3, sW2, 48)
    SILU16(B0v) SILU16(B1v) SILU16(B2v) SILU16(B3v)

    // ---- gate ----
    float g = GB;
    DOT16(g, B0v, sGW + 0) DOT16(g, B1v, sGW + 16) DOT16(g, B2v, sGW + 32) DOT16(g, B3v, sGW + 48)
    const float gate = sigmoidf_(g);
    MUL16(B0v, gate) MUL16(B1v, gate) MUL16(B2v, gate) MUL16(B3v, gate)

    // ---- q = silu(m2 @ PW1 + PB1); p = q @ PW2 ----
    LOAD16(A0, sPB1 + 0) LOAD16(A1, sPB1 + 16) LOAD16(A2, sPB1 + 32) LOAD16(A3, sPB1 + 48)
    GEMM16(A0,A1,A2,A3, B0v, sPW1, 0)
    GEMM16(A0,A1,A2,A3, B1v, sPW1, 16)
    GEMM16(A0,A1,A2,A3, B2v, sPW1, 32)
    GEMM16(A0,A1,A2,A3, B3v, sPW1, 48)
    SILU16(A0) SILU16(A1) SILU16(A2) SILU16(A3)
    float p = 0.f;
    DOT16(p, A0, sPW2 + 0) DOT16(p, A1, sPW2 + 16) DOT16(p, A2, sPW2 + 32) DOT16(p, A3, sPW2 + 48)

    float tx = fminf(fmaxf(rx * p, -2.0f), 2.0f);
    float ty = fminf(fmaxf(ry * p, -2.0f), 2.0f);
    float tz = fminf(fmaxf(rz * p, -2.0f), 2.0f);

    // ---- segmented reduction to run heads (edges sorted by dst) ----
    SEGSTEP(1) SEGSTEP(2) SEGSTEP(4) SEGSTEP(8) SEGSTEP(16) SEGSTEP(32)

    const int tprev = __shfl_up(tkey, 1);
    const bool head = ((lane == 0) || (tprev != tkey)) && (e < E);
    if (head) {
        atomicAdd(&pos_acc[t * 3 + 0], tx);
        atomicAdd(&pos_acc[t * 3 + 1], ty);
        atomicAdd(&pos_acc[t * 3 + 2], tz);
        float* arow = agg + ((size_t)c * N + t) * DH;
        ATOM16(arow + 0,  B0v)
        ATOM16(arow + 16, B1v)
        ATOM16(arow + 32, B2v)
        ATOM16(arow + 48, B3v)
    }
}

// ---------------- node update ----------------
__global__ __launch_bounds__(256) void node_kernel(
        const float* __restrict__ h, float* __restrict__ agg,
        const float* __restrict__ nw, const float* __restrict__ nb, int N) {
    const int c = blockIdx.y;
    const int wave = threadIdx.x >> 6, lane = threadIdx.x & 63;
    const int i = blockIdx.x * 4 + wave;
    if (i >= N) return;
    const float* hrow = h + ((size_t)c * N + i) * DH;
    float* arow = agg + ((size_t)c * N + i) * DH;
    const float* W = nw + (size_t)c * (2 * DH) * DH;
    float acc = nb[(size_t)c * DH + lane];
    #pragma unroll 8
    for (int k = 0; k < DH; ++k) acc += hrow[k] * W[(size_t)k * DH + lane];
    #pragma unroll 8
    for (int k = 0; k < DH; ++k) acc += arow[k] * W[(size_t)(DH + k) * DH + lane];
    arow[lane] = acc;
}

// ---------------- mix_out ----------------
__global__ __launch_bounds__(256) void mix_out_kernel(
        const float* __restrict__ hout, const float* __restrict__ W,
        float* __restrict__ x, int N) {
    __shared__ float hs[8][CC * DH];
    const int i0 = blockIdx.x * 8;
    const int tid = threadIdx.x;
    for (int t = tid; t < 8 * CC * DH; t += 256) {
        int j = t >> 8, cd = t & 255;
        int c = cd >> 6, d = cd & 63;
        int i = i0 + j;
        hs[j][cd] = (i < N) ? hout[((size_t)c * N + i) * DH + d] : 0.f;
    }
    __syncthreads();
    const int o = tid & 127, g = tid >> 7;
    float acc[4] = {0.f, 0.f, 0.f, 0.f};
    for (int cd = 0; cd < CC * DH; ++cd) {
        float w = W[(size_t)cd * DIN + o];
        #pragma unroll
        for (int j = 0; j < 4; ++j) acc[j] += hs[g * 4 + j][cd] * w;
    }
    #pragma unroll
    for (int j = 0; j < 4; ++j) {
        int i = i0 + g * 4 + j;
        if (i < N) x[(size_t)i * DIN + o] += acc[j];
    }
}

// ---------------- pos finalize ----------------
__global__ void pos_fin_kernel(float* __restrict__ pos, const float* __restrict__ pos_acc,
                               const int* __restrict__ cnt, int N) {
    int i = blockIdx.x * 256 + threadIdx.x;
    if (i < N) {
        float inv = 1.0f / ((float)CC * fmaxf((float)cnt[i], 1.0f));
        pos[i * 3 + 0] += pos_acc[i * 3 + 0] * inv;
        pos[i * 3 + 1] += pos_acc[i * 3 + 1] * inv;
        pos[i * 3 + 2] += pos_acc[i * 3 + 2] * inv;
    }
}

extern "C" void kernel_launch(void* const* d_in, const int* in_sizes, int n_in,
                              void* d_out, int out_size, void* d_ws, size_t ws_size,
                              hipStream_t stream) {
    const float* x         = (const float*)d_in[0];
    const float* pos       = (const float*)d_in[1];
    const int*   ei        = (const int*)d_in[2];
    const float* mix_in_w  = (const float*)d_in[3];
    const float* mix_out_w = (const float*)d_in[4];
    const float* ew1       = (const float*)d_in[5];
    const float* eb1       = (const float*)d_in[6];
    const float* ew2       = (const float*)d_in[7];
    const float* eb2       = (const float*)d_in[8];
    const float* gw        = (const float*)d_in[9];
    const float* gb        = (const float*)d_in[10];
    const float* nw        = (const float*)d_in[11];
    const float* nb        = (const float*)d_in[12];
    const float* pw1       = (const float*)d_in[13];
    const float* pb1       = (const float*)d_in[14];
    const float* pw2       = (const float*)d_in[15];

    const int* src = ei;
    const int* dst = ei + EE;

    float* xout    = (float*)d_out;                 // [N][128]
    float* pos_out = xout + (size_t)NN * DIN;       // [N][3]

    float* hbuf    = (float*)d_ws;                  // C*N*64
    float* aggb    = hbuf + (size_t)CC * NN * DH;   // C*N*64
    float* pos_cur = aggb + (size_t)CC * NN * DH;   // N*3
    float* pos_acc = pos_cur + (size_t)NN * 3;      // N*3
    int*   cnt_i   = (int*)(pos_acc + (size_t)NN * 3);  // N
    int*   offs    = cnt_i + NN;                    // N
    int*   fill    = offs + NN;                     // N
    int*   bsum    = fill + NN;                     // 256
    int*   ssrc    = bsum + 256;                    // E
    int*   sdst    = ssrc + EE;                     // E

    const int NB = (NN + 255) / 256;                // scan blocks

    hipMemcpyAsync(xout, x, sizeof(float) * NN * DIN, hipMemcpyDeviceToDevice, stream);
    hipMemcpyAsync(pos_cur, pos, sizeof(float) * NN * 3, hipMemcpyDeviceToDevice, stream);
    hipMemsetAsync(cnt_i, 0, sizeof(int) * NN, stream);
    hipMemsetAsync(fill, 0, sizeof(int) * NN, stream);

    cnt_kernel<<<(EE + 255) / 256, 256, 0, stream>>>(dst, cnt_i, EE);
    scan1<<<NB, 256, 0, stream>>>(cnt_i, offs, bsum, NN);
    scan2<<<1, 256, 0, stream>>>(bsum, NB);
    scan3<<<NB, 256, 0, stream>>>(offs, bsum, NN);
    order_kernel<<<(EE + 255) / 256, 256, 0, stream>>>(src, dst, offs, fill, ssrc, sdst, EE);

    for (int l = 0; l < LL; ++l) {
        hipMemsetAsync(aggb, 0, sizeof(float) * CC * NN * DH, stream);
        hipMemsetAsync(pos_acc, 0, sizeof(float) * NN * 3, stream);

        mix_in_kernel<<<(NN + 7) / 8, 256, 0, stream>>>(
            xout, mix_in_w + (size_t)l * DIN * CC * DH, hbuf, NN);

        edge_kernel<<<dim3((EE + 511) / 512, CC), 512, 0, stream>>>(
            hbuf, pos_cur, ssrc, sdst,
            ew1 + (size_t)l * CC * (2 * DH + 1) * DH,
            eb1 + (size_t)l * CC * DH,
            ew2 + (size_t)l * CC * DH * DH,
            eb2 + (size_t)l * CC * DH,
            gw  + (size_t)l * CC * DH,
            gb  + (size_t)l * CC,
            pw1 + (size_t)l * CC * DH * DH,
            pb1 + (size_t)l * CC * DH,
            pw2 + (size_t)l * CC * DH,
            aggb, pos_acc, EE, NN);

        node_kernel<<<dim3((NN + 3) / 4, CC), 256, 0, stream>>>(
            hbuf, aggb,
            nw + (size_t)l * CC * 2 * DH * DH,
            nb + (size_t)l * CC * DH, NN);

        mix_out_kernel<<<(NN + 7) / 8, 256, 0, stream>>>(
            aggb, mix_out_w + (size_t)l * CC * DH * DIN, xout, NN);

        pos_fin_kernel<<<(NN + 255) / 256, 256, 0, stream>>>(pos_cur, pos_acc, cnt_i, NN);
    }

    hipMemcpyAsync(pos_out, pos_cur, sizeof(float) * NN * 3, hipMemcpyDeviceToDevice, stream);
}

// Round 5
// 9364.210 us; speedup vs baseline: 1.5200x; 1.5200x over previous
//
#include <hip/hip_runtime.h>

#define NN 50000
#define EE 800000
#define DIN 128
#define DH 64
#define CC 4
#define LL 3

typedef float f32x16 __attribute__((ext_vector_type(16)));

__device__ __forceinline__ float sigmoidf_(float x) {
    return __builtin_amdgcn_rcpf(1.0f + __expf(-x));
}

// ---- register-resident 16-wide helpers (all vector indices are literals) ----
#define LOAD16(V, P) { const float4* _p4 = (const float4*)(P); \
    float4 _a=_p4[0], _b=_p4[1], _c=_p4[2], _d=_p4[3]; \
    V[0]=_a.x; V[1]=_a.y; V[2]=_a.z; V[3]=_a.w; \
    V[4]=_b.x; V[5]=_b.y; V[6]=_b.z; V[7]=_b.w; \
    V[8]=_c.x; V[9]=_c.y; V[10]=_c.z; V[11]=_c.w; \
    V[12]=_d.x; V[13]=_d.y; V[14]=_d.z; V[15]=_d.w; }

#define FMA16V(V, P, xv) { const float4* _w4 = (const float4*)(P); \
    float4 _w0=_w4[0], _w1=_w4[1], _w2=_w4[2], _w3=_w4[3]; \
    V[0]+=(xv)*_w0.x; V[1]+=(xv)*_w0.y; V[2]+=(xv)*_w0.z; V[3]+=(xv)*_w0.w; \
    V[4]+=(xv)*_w1.x; V[5]+=(xv)*_w1.y; V[6]+=(xv)*_w1.z; V[7]+=(xv)*_w1.w; \
    V[8]+=(xv)*_w2.x; V[9]+=(xv)*_w2.y; V[10]+=(xv)*_w2.z; V[11]+=(xv)*_w2.w; \
    V[12]+=(xv)*_w3.x; V[13]+=(xv)*_w3.y; V[14]+=(xv)*_w3.z; V[15]+=(xv)*_w3.w; }

#define FMA64V(V0,V1,V2,V3, ROWP, xv) { const float* _rp = (ROWP); const float _x = (xv); \
    FMA16V(V0, _rp+0, _x) FMA16V(V1, _rp+16, _x) FMA16V(V2, _rp+32, _x) FMA16V(V3, _rp+48, _x) }

#define SILU16(V) { \
    V[0]*=sigmoidf_(V[0]);  V[1]*=sigmoidf_(V[1]);  V[2]*=sigmoidf_(V[2]);  V[3]*=sigmoidf_(V[3]); \
    V[4]*=sigmoidf_(V[4]);  V[5]*=sigmoidf_(V[5]);  V[6]*=sigmoidf_(V[6]);  V[7]*=sigmoidf_(V[7]); \
    V[8]*=sigmoidf_(V[8]);  V[9]*=sigmoidf_(V[9]);  V[10]*=sigmoidf_(V[10]); V[11]*=sigmoidf_(V[11]); \
    V[12]*=sigmoidf_(V[12]); V[13]*=sigmoidf_(V[13]); V[14]*=sigmoidf_(V[14]); V[15]*=sigmoidf_(V[15]); }

#define MUL16(V, s) { \
    V[0]*=(s); V[1]*=(s); V[2]*=(s); V[3]*=(s); V[4]*=(s); V[5]*=(s); V[6]*=(s); V[7]*=(s); \
    V[8]*=(s); V[9]*=(s); V[10]*=(s); V[11]*=(s); V[12]*=(s); V[13]*=(s); V[14]*=(s); V[15]*=(s); }

#define DOT16(acc, V, P) { const float4* _g4 = (const float4*)(P); \
    float4 _g0=_g4[0], _g1=_g4[1], _g2=_g4[2], _g3=_g4[3]; \
    acc += V[0]*_g0.x + V[1]*_g0.y + V[2]*_g0.z + V[3]*_g0.w \
         + V[4]*_g1.x + V[5]*_g1.y + V[6]*_g1.z + V[7]*_g1.w \
         + V[8]*_g2.x + V[9]*_g2.y + V[10]*_g2.z + V[11]*_g2.w \
         + V[12]*_g3.x + V[13]*_g3.y + V[14]*_g3.z + V[15]*_g3.w; }

#define ATOM16(P, V) { \
    atomicAdd((P)+0,  V[0]);  atomicAdd((P)+1,  V[1]);  atomicAdd((P)+2,  V[2]);  atomicAdd((P)+3,  V[3]); \
    atomicAdd((P)+4,  V[4]);  atomicAdd((P)+5,  V[5]);  atomicAdd((P)+6,  V[6]);  atomicAdd((P)+7,  V[7]); \
    atomicAdd((P)+8,  V[8]);  atomicAdd((P)+9,  V[9]);  atomicAdd((P)+10, V[10]); atomicAdd((P)+11, V[11]); \
    atomicAdd((P)+12, V[12]); atomicAdd((P)+13, V[13]); atomicAdd((P)+14, V[14]); atomicAdd((P)+15, V[15]); }

#define GSTEP(D0,D1,D2,D3, W, kk, xv) FMA64V(D0,D1,D2,D3, (W)+(size_t)(kk)*DH, xv)
#define GEMM16(D0,D1,D2,D3, S, W, ko) \
    GSTEP(D0,D1,D2,D3, W, (ko)+0,  S[0])  GSTEP(D0,D1,D2,D3, W, (ko)+1,  S[1])  \
    GSTEP(D0,D1,D2,D3, W, (ko)+2,  S[2])  GSTEP(D0,D1,D2,D3, W, (ko)+3,  S[3])  \
    GSTEP(D0,D1,D2,D3, W, (ko)+4,  S[4])  GSTEP(D0,D1,D2,D3, W, (ko)+5,  S[5])  \
    GSTEP(D0,D1,D2,D3, W, (ko)+6,  S[6])  GSTEP(D0,D1,D2,D3, W, (ko)+7,  S[7])  \
    GSTEP(D0,D1,D2,D3, W, (ko)+8,  S[8])  GSTEP(D0,D1,D2,D3, W, (ko)+9,  S[9])  \
    GSTEP(D0,D1,D2,D3, W, (ko)+10, S[10]) GSTEP(D0,D1,D2,D3, W, (ko)+11, S[11]) \
    GSTEP(D0,D1,D2,D3, W, (ko)+12, S[12]) GSTEP(D0,D1,D2,D3, W, (ko)+13, S[13]) \
    GSTEP(D0,D1,D2,D3, W, (ko)+14, S[14]) GSTEP(D0,D1,D2,D3, W, (ko)+15, S[15])

// ---- segmented wave reduction (dst-sorted edges; reduce run -> head lane) ----
#define SEG16(V, S, okf) { \
    float _r0=__shfl_down(V[0],S),  _r1=__shfl_down(V[1],S),  _r2=__shfl_down(V[2],S),  _r3=__shfl_down(V[3],S), \
          _r4=__shfl_down(V[4],S),  _r5=__shfl_down(V[5],S),  _r6=__shfl_down(V[6],S),  _r7=__shfl_down(V[7],S), \
          _r8=__shfl_down(V[8],S),  _r9=__shfl_down(V[9],S),  _r10=__shfl_down(V[10],S), _r11=__shfl_down(V[11],S), \
          _r12=__shfl_down(V[12],S), _r13=__shfl_down(V[13],S), _r14=__shfl_down(V[14],S), _r15=__shfl_down(V[15],S); \
    V[0]=fmaf(okf,_r0,V[0]);   V[1]=fmaf(okf,_r1,V[1]);   V[2]=fmaf(okf,_r2,V[2]);   V[3]=fmaf(okf,_r3,V[3]); \
    V[4]=fmaf(okf,_r4,V[4]);   V[5]=fmaf(okf,_r5,V[5]);   V[6]=fmaf(okf,_r6,V[6]);   V[7]=fmaf(okf,_r7,V[7]); \
    V[8]=fmaf(okf,_r8,V[8]);   V[9]=fmaf(okf,_r9,V[9]);   V[10]=fmaf(okf,_r10,V[10]); V[11]=fmaf(okf,_r11,V[11]); \
    V[12]=fmaf(okf,_r12,V[12]); V[13]=fmaf(okf,_r13,V[13]); V[14]=fmaf(okf,_r14,V[14]); V[15]=fmaf(okf,_r15,V[15]); }

#define SEGSTEP(S) { \
    int _tn = __shfl_down(t, S); \
    float _ok = ((lane + S < 64) && (_tn == t)) ? 1.0f : 0.0f; \
    SEG16(B0v, S, _ok) SEG16(B1v, S, _ok) SEG16(B2v, S, _ok) SEG16(B3v, S, _ok) \
    { float _a=__shfl_down(tx,S), _b=__shfl_down(ty,S), _c=__shfl_down(tz,S); \
      tx=fmaf(_ok,_a,tx); ty=fmaf(_ok,_b,ty); tz=fmaf(_ok,_c,tz); } }

// ---------------- degree count (once per launch) ----------------
__global__ void cnt_kernel(const int* __restrict__ dst, int* __restrict__ cnt, int E) {
    int e = blockIdx.x * 256 + threadIdx.x;
    if (e < E) atomicAdd(&cnt[dst[e]], 1);
}

// ---------------- 3-step exclusive scan of cnt -> offs ----------------
__global__ __launch_bounds__(256) void scan1(const int* __restrict__ cnt, int* __restrict__ offs,
                                             int* __restrict__ bsum, int N) {
    __shared__ int sh[256];
    int i = blockIdx.x * 256 + threadIdx.x;
    int v = (i < N) ? cnt[i] : 0;
    sh[threadIdx.x] = v; __syncthreads();
    for (int s = 1; s < 256; s <<= 1) {
        int a = (threadIdx.x >= s) ? sh[threadIdx.x - s] : 0;
        __syncthreads(); sh[threadIdx.x] += a; __syncthreads();
    }
    int incl = sh[threadIdx.x];
    if (i < N) offs[i] = incl - v;
    if (threadIdx.x == 255) bsum[blockIdx.x] = incl;
}
__global__ __launch_bounds__(256) void scan2(int* __restrict__ bsum, int nb) {
    __shared__ int sh[256];
    int v = (threadIdx.x < nb) ? bsum[threadIdx.x] : 0;
    sh[threadIdx.x] = v; __syncthreads();
    for (int s = 1; s < 256; s <<= 1) {
        int a = (threadIdx.x >= s) ? sh[threadIdx.x - s] : 0;
        __syncthreads(); sh[threadIdx.x] += a; __syncthreads();
    }
    if (threadIdx.x < nb) bsum[threadIdx.x] = sh[threadIdx.x] - v;
}
__global__ void scan3(int* __restrict__ offs, const int* __restrict__ bsum, int N) {
    int i = blockIdx.x * 256 + threadIdx.x;
    if (i < N) offs[i] += bsum[blockIdx.x];
}

// ---------------- counting-sort edges by dst ----------------
__global__ void order_kernel(const int* __restrict__ src, const int* __restrict__ dst,
                             const int* __restrict__ offs, int* __restrict__ fill,
                             int* __restrict__ ssrc, int* __restrict__ sdst, int E) {
    int e = blockIdx.x * 256 + threadIdx.x;
    if (e < E) {
        int d = dst[e];
        int slot = offs[d] + atomicAdd(&fill[d], 1);
        ssrc[slot] = src[e];
        sdst[slot] = d;
    }
}

// ---------------- mix_in ----------------
__global__ __launch_bounds__(256) void mix_in_kernel(
        const float* __restrict__ x, const float* __restrict__ W,
        float* __restrict__ h, int N) {
    __shared__ float xs[8][DIN];
    const int i0 = blockIdx.x * 8;
    const int tid = threadIdx.x;
    for (int t = tid; t < 8 * DIN; t += 256) {
        int j = t / DIN, k = t % DIN;
        int i = i0 + j;
        xs[j][k] = (i < N) ? x[(size_t)i * DIN + k] : 0.f;
    }
    __syncthreads();
    float acc[8] = {0.f, 0.f, 0.f, 0.f, 0.f, 0.f, 0.f, 0.f};
    for (int k = 0; k < DIN; ++k) {
        float w = W[k * (CC * DH) + tid];
        #pragma unroll
        for (int j = 0; j < 8; ++j) acc[j] += xs[j][k] * w;
    }
    const int c = tid >> 6, d = tid & 63;
    #pragma unroll
    for (int j = 0; j < 8; ++j) {
        int i = i0 + j;
        if (i < N) h[((size_t)c * N + i) * DH + d] = acc[j];
    }
}

// ---------------- edge kernel: LDS weights + 256 thr (no VGPR cap squeeze) ----------------
// E % 256 == 0, so no tail masking; every wave is full.
__global__ __launch_bounds__(256, 2) void edge_kernel(
    const float* __restrict__ h, const float* __restrict__ pos,
    const int* __restrict__ ssrc, const int* __restrict__ sdst,
    const float* __restrict__ ew1, const float* __restrict__ eb1,
    const float* __restrict__ ew2, const float* __restrict__ eb2,
    const float* __restrict__ gw,  const float* __restrict__ gb,
    const float* __restrict__ pw1, const float* __restrict__ pb1,
    const float* __restrict__ pw2,
    float* __restrict__ agg, float* __restrict__ pos_acc,
    int E, int N)
{
    __shared__ float sW1[(2 * DH + 1) * DH];   // 8256 floats = 33 KB
    __shared__ float sW2[DH * DH];             // 16 KB
    __shared__ float sPW1[DH * DH];            // 16 KB
    __shared__ float sB1[DH], sB2[DH], sPB1[DH], sGW[DH], sPW2[DH];

    const int c = blockIdx.y;
    const int tid = threadIdx.x;

    // ---- stage weights to LDS (coalesced float4 copies) ----
    {
        const float4* g1 = (const float4*)(ew1 + (size_t)c * (2 * DH + 1) * DH);
        float4* l1 = (float4*)sW1;
        #pragma unroll
        for (int i = 0; i < 9; ++i) { int idx = tid + i * 256; if (idx < 2064) l1[idx] = g1[idx]; }
        const float4* g2 = (const float4*)(ew2 + (size_t)c * DH * DH);
        float4* l2 = (float4*)sW2;
        #pragma unroll
        for (int i = 0; i < 4; ++i) l2[tid + i * 256] = g2[tid + i * 256];
        const float4* g3 = (const float4*)(pw1 + (size_t)c * DH * DH);
        float4* l3 = (float4*)sPW1;
        #pragma unroll
        for (int i = 0; i < 4; ++i) l3[tid + i * 256] = g3[tid + i * 256];
        if (tid < DH) {
            sB1[tid]  = eb1[(size_t)c * DH + tid];
            sB2[tid]  = eb2[(size_t)c * DH + tid];
            sPB1[tid] = pb1[(size_t)c * DH + tid];
            sGW[tid]  = gw[(size_t)c * DH + tid];
            sPW2[tid] = pw2[(size_t)c * DH + tid];
        }
    }
    __syncthreads();

    const int e = blockIdx.x * 256 + tid;
    const int lane = tid & 63;
    const int s = ssrc[e];
    const int t = sdst[e];

    const float rx = pos[s * 3 + 0] - pos[t * 3 + 0];
    const float ry = pos[s * 3 + 1] - pos[t * 3 + 1];
    const float rz = pos[s * 3 + 2] - pos[t * 3 + 2];
    const float d2 = rx * rx + ry * ry + rz * rz;

    const float GB = gb[c];
    const float4* hs4 = (const float4*)(h + ((size_t)c * N + s) * DH);
    const float4* hd4 = (const float4*)(h + ((size_t)c * N + t) * DH);

    // ---- m1 = silu([h_s, h_d, d2] @ W1 + B1) ----
    f32x16 A0, A1, A2, A3;
    LOAD16(A0, sB1 + 0) LOAD16(A1, sB1 + 16) LOAD16(A2, sB1 + 32) LOAD16(A3, sB1 + 48)
    #pragma unroll 2
    for (int k4 = 0; k4 < 16; ++k4) {
        const float4 xa = hs4[k4];
        FMA64V(A0,A1,A2,A3, sW1 + (size_t)(k4*4+0)*DH, xa.x)
        FMA64V(A0,A1,A2,A3, sW1 + (size_t)(k4*4+1)*DH, xa.y)
        FMA64V(A0,A1,A2,A3, sW1 + (size_t)(k4*4+2)*DH, xa.z)
        FMA64V(A0,A1,A2,A3, sW1 + (size_t)(k4*4+3)*DH, xa.w)
    }
    #pragma unroll 2
    for (int k4 = 0; k4 < 16; ++k4) {
        const float4 xa = hd4[k4];
        FMA64V(A0,A1,A2,A3, sW1 + (size_t)(DH + k4*4+0)*DH, xa.x)
        FMA64V(A0,A1,A2,A3, sW1 + (size_t)(DH + k4*4+1)*DH, xa.y)
        FMA64V(A0,A1,A2,A3, sW1 + (size_t)(DH + k4*4+2)*DH, xa.z)
        FMA64V(A0,A1,A2,A3, sW1 + (size_t)(DH + k4*4+3)*DH, xa.w)
    }
    FMA64V(A0,A1,A2,A3, sW1 + (size_t)(2*DH)*DH, d2)
    SILU16(A0) SILU16(A1) SILU16(A2) SILU16(A3)

    // ---- m2 = silu(m1 @ W2 + B2) ----
    f32x16 B0v, B1v, B2v, B3v;
    LOAD16(B0v, sB2 + 0) LOAD16(B1v, sB2 + 16) LOAD16(B2v, sB2 + 32) LOAD16(B3v, sB2 + 48)
    GEMM16(B0v,B1v,B2v,B3v, A0, sW2, 0)
    GEMM16(B0v,B1v,B2v,B3v, A1, sW2, 16)
    GEMM16(B0v,B1v,B2v,B3v, A2, sW2, 32)
    GEMM16(B0v,B1v,B2v,B3v, A3, sW2, 48)
    SILU16(B0v) SILU16(B1v) SILU16(B2v) SILU16(B3v)

    // ---- gate ----
    float g = GB;
    DOT16(g, B0v, sGW + 0) DOT16(g, B1v, sGW + 16) DOT16(g, B2v, sGW + 32) DOT16(g, B3v, sGW + 48)
    const float gate = sigmoidf_(g);
    MUL16(B0v, gate) MUL16(B1v, gate) MUL16(B2v, gate) MUL16(B3v, gate)

    // ---- q = silu(m2 @ PW1 + PB1); p = q @ PW2 ----
    LOAD16(A0, sPB1 + 0) LOAD16(A1, sPB1 + 16) LOAD16(A2, sPB1 + 32) LOAD16(A3, sPB1 + 48)
    GEMM16(A0,A1,A2,A3, B0v, sPW1, 0)
    GEMM16(A0,A1,A2,A3, B1v, sPW1, 16)
    GEMM16(A0,A1,A2,A3, B2v, sPW1, 32)
    GEMM16(A0,A1,A2,A3, B3v, sPW1, 48)
    SILU16(A0) SILU16(A1) SILU16(A2) SILU16(A3)
    float p = 0.f;
    DOT16(p, A0, sPW2 + 0) DOT16(p, A1, sPW2 + 16) DOT16(p, A2, sPW2 + 32) DOT16(p, A3, sPW2 + 48)

    float tx = fminf(fmaxf(rx * p, -2.0f), 2.0f);
    float ty = fminf(fmaxf(ry * p, -2.0f), 2.0f);
    float tz = fminf(fmaxf(rz * p, -2.0f), 2.0f);

    // ---- segmented reduction to run heads (edges sorted by dst) ----
    SEGSTEP(1) SEGSTEP(2) SEGSTEP(4) SEGSTEP(8) SEGSTEP(16) SEGSTEP(32)

    const int tprev = __shfl_up(t, 1);
    const bool head = (lane == 0) || (tprev != t);
    if (head) {
        atomicAdd(&pos_acc[t * 3 + 0], tx);
        atomicAdd(&pos_acc[t * 3 + 1], ty);
        atomicAdd(&pos_acc[t * 3 + 2], tz);
        float* arow = agg + ((size_t)c * N + t) * DH;
        ATOM16(arow + 0,  B0v)
        ATOM16(arow + 16, B1v)
        ATOM16(arow + 32, B2v)
        ATOM16(arow + 48, B3v)
    }
}

// ---------------- node update ----------------
__global__ __launch_bounds__(256) void node_kernel(
        const float* __restrict__ h, float* __restrict__ agg,
        const float* __restrict__ nw, const float* __restrict__ nb, int N) {
    const int c = blockIdx.y;
    const int wave = threadIdx.x >> 6, lane = threadIdx.x & 63;
    const int i = blockIdx.x * 4 + wave;
    if (i >= N) return;
    const float* hrow = h + ((size_t)c * N + i) * DH;
    float* arow = agg + ((size_t)c * N + i) * DH;
    const float* W = nw + (size_t)c * (2 * DH) * DH;
    float acc = nb[(size_t)c * DH + lane];
    #pragma unroll 8
    for (int k = 0; k < DH; ++k) acc += hrow[k] * W[(size_t)k * DH + lane];
    #pragma unroll 8
    for (int k = 0; k < DH; ++k) acc += arow[k] * W[(size_t)(DH + k) * DH + lane];
    arow[lane] = acc;
}

// ---------------- mix_out ----------------
__global__ __launch_bounds__(256) void mix_out_kernel(
        const float* __restrict__ hout, const float* __restrict__ W,
        float* __restrict__ x, int N) {
    __shared__ float hs[8][CC * DH];
    const int i0 = blockIdx.x * 8;
    const int tid = threadIdx.x;
    for (int t = tid; t < 8 * CC * DH; t += 256) {
        int j = t >> 8, cd = t & 255;
        int c = cd >> 6, d = cd & 63;
        int i = i0 + j;
        hs[j][cd] = (i < N) ? hout[((size_t)c * N + i) * DH + d] : 0.f;
    }
    __syncthreads();
    const int o = tid & 127, g = tid >> 7;
    float acc[4] = {0.f, 0.f, 0.f, 0.f};
    for (int cd = 0; cd < CC * DH; ++cd) {
        float w = W[(size_t)cd * DIN + o];
        #pragma unroll
        for (int j = 0; j < 4; ++j) acc[j] += hs[g * 4 + j][cd] * w;
    }
    #pragma unroll
    for (int j = 0; j < 4; ++j) {
        int i = i0 + g * 4 + j;
        if (i < N) x[(size_t)i * DIN + o] += acc[j];
    }
}

// ---------------- pos finalize ----------------
__global__ void pos_fin_kernel(float* __restrict__ pos, const float* __restrict__ pos_acc,
                               const int* __restrict__ cnt, int N) {
    int i = blockIdx.x * 256 + threadIdx.x;
    if (i < N) {
        float inv = 1.0f / ((float)CC * fmaxf((float)cnt[i], 1.0f));
        pos[i * 3 + 0] += pos_acc[i * 3 + 0] * inv;
        pos[i * 3 + 1] += pos_acc[i * 3 + 1] * inv;
        pos[i * 3 + 2] += pos_acc[i * 3 + 2] * inv;
    }
}

extern "C" void kernel_launch(void* const* d_in, const int* in_sizes, int n_in,
                              void* d_out, int out_size, void* d_ws, size_t ws_size,
                              hipStream_t stream) {
    const float* x         = (const float*)d_in[0];
    const float* pos       = (const float*)d_in[1];
    const int*   ei        = (const int*)d_in[2];
    const float* mix_in_w  = (const float*)d_in[3];
    const float* mix_out_w = (const float*)d_in[4];
    const float* ew1       = (const float*)d_in[5];
    const float* eb1       = (const float*)d_in[6];
    const float* ew2       = (const float*)d_in[7];
    const float* eb2       = (const float*)d_in[8];
    const float* gw        = (const float*)d_in[9];
    const float* gb        = (const float*)d_in[10];
    const float* nw        = (const float*)d_in[11];
    const float* nb        = (const float*)d_in[12];
    const float* pw1       = (const float*)d_in[13];
    const float* pb1       = (const float*)d_in[14];
    const float* pw2       = (const float*)d_in[15];

    const int* src = ei;
    const int* dst = ei + EE;

    float* xout    = (float*)d_out;                 // [N][128]
    float* pos_out = xout + (size_t)NN * DIN;       // [N][3]

    float* hbuf    = (float*)d_ws;                  // C*N*64
    float* aggb    = hbuf + (size_t)CC * NN * DH;   // C*N*64
    float* pos_cur = aggb + (size_t)CC * NN * DH;   // N*3
    float* pos_acc = pos_cur + (size_t)NN * 3;      // N*3
    int*   cnt_i   = (int*)(pos_acc + (size_t)NN * 3);  // N
    int*   offs    = cnt_i + NN;                    // N
    int*   fill    = offs + NN;                     // N
    int*   bsum    = fill + NN;                     // 256
    int*   ssrc    = bsum + 256;                    // E
    int*   sdst    = ssrc + EE;                     // E

    const int NB = (NN + 255) / 256;                // scan blocks

    hipMemcpyAsync(xout, x, sizeof(float) * NN * DIN, hipMemcpyDeviceToDevice, stream);
    hipMemcpyAsync(pos_cur, pos, sizeof(float) * NN * 3, hipMemcpyDeviceToDevice, stream);
    hipMemsetAsync(cnt_i, 0, sizeof(int) * NN, stream);
    hipMemsetAsync(fill, 0, sizeof(int) * NN, stream);

    cnt_kernel<<<(EE + 255) / 256, 256, 0, stream>>>(dst, cnt_i, EE);
    scan1<<<NB, 256, 0, stream>>>(cnt_i, offs, bsum, NN);
    scan2<<<1, 256, 0, stream>>>(bsum, NB);
    scan3<<<NB, 256, 0, stream>>>(offs, bsum, NN);
    order_kernel<<<(EE + 255) / 256, 256, 0, stream>>>(src, dst, offs, fill, ssrc, sdst, EE);

    for (int l = 0; l < LL; ++l) {
        hipMemsetAsync(aggb, 0, sizeof(float) * CC * NN * DH, stream);
        hipMemsetAsync(pos_acc, 0, sizeof(float) * NN * 3, stream);

        mix_in_kernel<<<(NN + 7) / 8, 256, 0, stream>>>(
            xout, mix_in_w + (size_t)l * DIN * CC * DH, hbuf, NN);

        edge_kernel<<<dim3(EE / 256, CC), 256, 0, stream>>>(
            hbuf, pos_cur, ssrc, sdst,
            ew1 + (size_t)l * CC * (2 * DH + 1) * DH,
            eb1 + (size_t)l * CC * DH,
            ew2 + (size_t)l * CC * DH * DH,
            eb2 + (size_t)l * CC * DH,
            gw  + (size_t)l * CC * DH,
            gb  + (size_t)l * CC,
            pw1 + (size_t)l * CC * DH * DH,
            pb1 + (size_t)l * CC * DH,
            pw2 + (size_t)l * CC * DH,
            aggb, pos_acc, EE, NN);

        node_kernel<<<dim3((NN + 3) / 4, CC), 256, 0, stream>>>(
            hbuf, aggb,
            nw + (size_t)l * CC * 2 * DH * DH,
            nb + (size_t)l * CC * DH, NN);

        mix_out_kernel<<<(NN + 7) / 8, 256, 0, stream>>>(
            aggb, mix_out_w + (size_t)l * CC * DH * DIN, xout, NN);

        pos_fin_kernel<<<(NN + 255) / 256, 256, 0, stream>>>(pos_cur, pos_acc, cnt_i, NN);
    }

    hipMemcpyAsync(pos_out, pos_cur, sizeof(float) * NN * 3, hipMemcpyDeviceToDevice, stream);
}